// Round 18
// baseline (385.995 us; speedup 1.0000x reference)
//
#include <hip/hip_runtime.h>
#include <hip/hip_bf16.h>

typedef unsigned short u16;
typedef unsigned int   u32;
typedef short bf16x8 __attribute__((ext_vector_type(8)));
typedef float f32x4  __attribute__((ext_vector_type(4)));

#define O_N    4
#define D_K    128
#define D_V    512
#define BANK   7200
#define NQ     3600
#define NT     64            // query columns per block
#define NTILES 57            // ceil(3600/64)
#define NSUB   225           // 7200 / 32 sub-tiles
#define VH_ROWS 256          // v rows per block (half of 512)

// ---- LDS layout (bytes). K/V are global->reg; LDS is P exchange only.
// P quad-tile: 2 buffer-sets x 2 unit-tiles x 8KB ([64 n][64 b] bf16, 128B rows)
#define P_OFF    0
#define LST_OFF  32768       // l stage [4 waves][64 n] f32 (1024)
#define MST_OFF  33792       // mm stage [4][64] f32 (1024)
#define SMEM_BYTES 34816     // x2 blocks = 68KB <= 160KB
#define Q_OFF    0           // Q tile (16KB) overlaps P; prologue only

#define MFMA16(a, b, c) __builtin_amdgcn_mfma_f32_16x16x32_bf16((a), (b), (c), 0, 0, 0)

static __device__ __forceinline__ u16 f2bf(float x) {
    u32 u = __builtin_bit_cast(u32, x);
    return (u16)((u + 0x7FFFu + ((u >> 16) & 1u)) >> 16);
}

// Q-side scale fold: stage Q * (log2e / sqrt(128)) so softmax exp is bare exp2f.
#define QSCALE 0.12751743f

// ---------------- preconv kernels ----------------

__global__ void k_transpose_bf16(const float* __restrict__ in, u16* __restrict__ out) {
    __shared__ float tile[32][33];
    const int obj = blockIdx.z;
    const float* src = in + (size_t)obj * D_K * BANK;
    u16* dst = out + (size_t)obj * BANK * D_K;
    const int bx = blockIdx.x * 32;   // bank
    const int by = blockIdx.y * 32;   // d
    const int tx = threadIdx.x, ty = threadIdx.y;  // 32 x 8
#pragma unroll
    for (int i = 0; i < 4; i++)
        tile[ty + 8 * i][tx] = src[(size_t)(by + ty + 8 * i) * BANK + bx + tx];
    __syncthreads();
#pragma unroll
    for (int i = 0; i < 4; i++)
        dst[(size_t)(bx + ty + 8 * i) * D_K + by + tx] = f2bf(tile[tx][ty + 8 * i]);
}

__global__ void k_convert_bf16(const float* __restrict__ in, u16* __restrict__ out, int n4) {
    int idx = blockIdx.x * blockDim.x + threadIdx.x;
    int stride = gridDim.x * blockDim.x;
    for (int i = idx; i < n4; i += stride) {
        float4 v = reinterpret_cast<const float4*>(in)[i];
        ushort4 o;
        o.x = f2bf(v.x); o.y = f2bf(v.y); o.z = f2bf(v.z); o.w = f2bf(v.w);
        reinterpret_cast<ushort4*>(out)[i] = o;
    }
}

__global__ void k_zero(float* out, int n) {
    int i = blockIdx.x * blockDim.x + threadIdx.x;
    if (i < n) out[i] = 0.f;
}

// ---------------- main fused kernel ----------------
// blockIdx.x = ((tile*G + g) << 3) | (o*2+vh): (o,vh) pinned per XCD for L2.
//
// R18 = R16 with ONE barrier per 128 banks (pair of R16's 64-bank unit
// bodies between rendezvous). Evidence: per-phase wall ~3500cy vs ~1200cy
// issue, and R5->R7's banks-per-barrier doubling bought 9% — amortize the
// all-wave rendezvous over 2x work. P is quad-tiled (2 buf-sets x 2 unit
// tiles); every R16 ordering invariant kept: kf covered by PV, V loads
// covered by next-phase QK + barrier, NO vmcnt fences (consumers drain via
// compiler-counted waits). Register audit: qf64 + V64 + kf16(transient) +
// ~40 misc ~= 185 arch + 64 acc <= 256 cap at (256,2) — no spill expected
// (tripwire: WRITE_SIZE).
__launch_bounds__(256, 2)
__global__ void k_matcher(const u16* __restrict__ Kt,     // [O][7200][128] bf16
                          const u16* __restrict__ Vb,     // [O][512][7200] bf16
                          const float* __restrict__ masks,// [O][7200]
                          const float* __restrict__ q_in, // [128][3600]
                          const float* __restrict__ q_out,// [512][3600]
                          float* __restrict__ out,        // [O][1024][3600]
                          int G, float* __restrict__ lw, float* __restrict__ mw)
{
    __shared__ __align__(16) char smem[SMEM_BYTES];
    const int tid  = threadIdx.x;
    const int wave = tid >> 6;
    const int lane = tid & 63;
    const int q    = lane >> 4;
    const int lr   = lane & 15;
    const int lr7  = lr & 7;

    const int grp  = blockIdx.x & 7;
    const int o    = grp >> 1;
    const int vh   = grp & 1;
    const int rest = blockIdx.x >> 3;
    const int tile = rest / G;
    const int g    = rest - tile * G;
    const int n0   = tile * NT;

    const bool needLM = (G == 1) || (vh == 0);

    // sub-tile (32-bank) range; pairs = 128-bank iterations; rem in {0,1}
    // (NSUB=225 with G in {1,2} gives cnt in {112,113,225}).
    const int st0 = (NSUB * g) / G;
    const int st1 = (NSUB * (g + 1)) / G;
    const int cnt = st1 - st0;
    const int npair = cnt >> 2;
    const int rem   = cnt & 3;    // 0 or 1 only for our configs

    // ---- stage Q tile (pre-scaled): Q_lds[n][d] bf16, granule swizzle ^ (n&7)
    for (int idx = tid; idx < NT * D_K; idx += 256) {
        int d = idx >> 6;
        int n = idx & 63;
        int gn = n0 + n;
        float v = (gn < NQ) ? q_in[(size_t)d * NQ + gn] * QSCALE : 0.f;
        int bb = d * 2;
        int sb = n * 256 + ((((bb >> 4) ^ (n & 7)) << 4) | (bb & 15));
        *reinterpret_cast<u16*>(smem + Q_OFF + sb) = f2bf(v);
    }
    __syncthreads();

    // ---- Q fragments for ALL 4 column groups (qf[cg][ds], 64 VGPRs)
    bf16x8 qf[4][4];
#pragma unroll
    for (int cg = 0; cg < 4; cg++)
#pragma unroll
        for (int ds = 0; ds < 4; ds++) {
            int gq = (4 * ds + q) ^ lr7;   // (16cg+lr)&7 == lr7
            qf[cg][ds] = *reinterpret_cast<const bf16x8*>(
                smem + Q_OFF + (16 * cg + lr) * 256 + gq * 16);
        }
    __syncthreads();   // Q region about to be overwritten by P tiles

    const f32x4 zero4 = {0.f, 0.f, 0.f, 0.f};
    f32x4 acc[4][4];
#pragma unroll
    for (int i = 0; i < 4; i++)
#pragma unroll
        for (int j = 0; j < 4; j++) acc[i][j] = zero4;
    float l_part[4]  = {0.f, 0.f, 0.f, 0.f};
    float mm_part[4] = {0.f, 0.f, 0.f, 0.f};

    const u16* Ko = Kt + (size_t)o * BANK * D_K;
    const u16* Vo = Vb + (size_t)o * D_V * BANK + (size_t)vh * VH_ROWS * BANK;

    // K direct-to-register: uniform advancing base + per-lane offset.
    const u16* Krow = Ko + (size_t)(st0 * 32) * D_K;
    const u32  kOff = (u32)(16 * wave + lr) * D_K + q * 8;

    // V direct-to-register: wave owns v rows [64w, 64w+64).
    const u16* Vrow = Vo + st0 * 32;
    const u32  vOff = (u32)(64 * wave + lr) * BANK + q * 8;

    // mask: lane's banks are ub + 16*wave + 4*q + r (r=0..3)
    const float* mPtr = masks + (size_t)o * BANK + st0 * 32 + 16 * wave + 4 * q;

// QK for one column group CG into P tile PWB: 4 MFMA over d, exp2, l/mm,
// cvt_pk, b64 P write.
#define QK_CG(CG, PWB) do {                                                  \
        f32x4 s_acc = zero4;                                                 \
        s_acc = MFMA16(kf0, qf[CG][0], s_acc);                               \
        s_acc = MFMA16(kf1, qf[CG][1], s_acc);                               \
        s_acc = MFMA16(kf2, qf[CG][2], s_acc);                               \
        s_acc = MFMA16(kf3, qf[CG][3], s_acc);                               \
        float p0 = exp2f(s_acc[0]);                                          \
        float p1 = exp2f(s_acc[1]);                                          \
        float p2 = exp2f(s_acc[2]);                                          \
        float p3 = exp2f(s_acc[3]);                                          \
        if (needLM) {                                                        \
            l_part[CG]  += p0 + p1 + p2 + p3;                                \
            mm_part[CG] += p0 * mv.x + p1 * mv.y + p2 * mv.z + p3 * mv.w;    \
        }                                                                    \
        u32 w0, w1;                                                          \
        asm("v_cvt_pk_bf16_f32 %0, %1, %2" : "=v"(w0) : "v"(p0), "v"(p1));   \
        asm("v_cvt_pk_bf16_f32 %0, %1, %2" : "=v"(w1) : "v"(p2), "v"(p3));   \
        uint2 pk2; pk2.x = w0; pk2.y = w1;                                   \
        *reinterpret_cast<uint2*>((PWB) + (16 * (CG) + lr) * 128 +           \
            (((2 * wave + (q >> 1)) ^ lr7) << 4) + (q & 1) * 8) = pk2;       \
    } while (0)

// PV for one 32-bank sub S from P tile PB with V frags V0..V3
#define PV_S(S, PB, V0, V1, V2, V3) do {                                     \
        _Pragma("unroll")                                                    \
        for (int ng = 0; ng < 4; ng++) {                                     \
            bf16x8 pf = *reinterpret_cast<const bf16x8*>(                    \
                (PB) + (16 * ng + lr) * 128 +                                \
                (((4 * (S) + q) ^ lr7) << 4));                               \
            acc[0][ng] = MFMA16(V0, pf, acc[0][ng]);                         \
            acc[1][ng] = MFMA16(V1, pf, acc[1][ng]);                         \
            acc[2][ng] = MFMA16(V2, pf, acc[2][ng]);                         \
            acc[3][ng] = MFMA16(V3, pf, acc[3][ng]);                         \
        }                                                                    \
    } while (0)

    // V frag sets for the two units of the current pair (live across barrier)
    bf16x8 Ava0, Ava1, Ava2, Ava3, Avb0, Avb1, Avb2, Avb3;
    bf16x8 Bva0, Bva1, Bva2, Bva3, Bvb0, Bvb1, Bvb2, Bvb3;

    for (int t = 0; t < npair; t++) {
        const int cur = t & 1;
        char* pC = smem + P_OFF + cur * 16384;
        const char* pP = smem + P_OFF + (cur ^ 1) * 16384;

        // ======== unit 0 of pair (banks +0..63) ========
        {
            bf16x8 kf0 = *reinterpret_cast<const bf16x8*>(Krow + kOff);
            bf16x8 kf1 = *reinterpret_cast<const bf16x8*>(Krow + kOff + 32);
            bf16x8 kf2 = *reinterpret_cast<const bf16x8*>(Krow + kOff + 64);
            bf16x8 kf3 = *reinterpret_cast<const bf16x8*>(Krow + kOff + 96);
            float4 mv = *reinterpret_cast<const float4*>(mPtr);
            __builtin_amdgcn_sched_barrier(0);
            if (t > 0) {
                __builtin_amdgcn_s_setprio(1);
                PV_S(0, pP, Ava0, Ava1, Ava2, Ava3);
                PV_S(1, pP, Avb0, Avb1, Avb2, Avb3);
                __builtin_amdgcn_s_setprio(0);
            }
            __builtin_amdgcn_sched_barrier(0);   // V loads below reuse Av* regs
            Ava0 = *reinterpret_cast<const bf16x8*>(Vrow + vOff);
            Ava1 = *reinterpret_cast<const bf16x8*>(Vrow + vOff + 16 * BANK);
            Ava2 = *reinterpret_cast<const bf16x8*>(Vrow + vOff + 32 * BANK);
            Ava3 = *reinterpret_cast<const bf16x8*>(Vrow + vOff + 48 * BANK);
            Avb0 = *reinterpret_cast<const bf16x8*>(Vrow + vOff + 32);
            Avb1 = *reinterpret_cast<const bf16x8*>(Vrow + vOff + 32 + 16 * BANK);
            Avb2 = *reinterpret_cast<const bf16x8*>(Vrow + vOff + 32 + 32 * BANK);
            Avb3 = *reinterpret_cast<const bf16x8*>(Vrow + vOff + 32 + 48 * BANK);
            __builtin_amdgcn_s_setprio(1);
            QK_CG(0, pC); QK_CG(1, pC); QK_CG(2, pC); QK_CG(3, pC);
            __builtin_amdgcn_s_setprio(0);
            Krow += 64 * D_K; Vrow += 64; mPtr += 64;
        }

        // ======== unit 1 of pair (banks +64..127) ========
        {
            bf16x8 kf0 = *reinterpret_cast<const bf16x8*>(Krow + kOff);
            bf16x8 kf1 = *reinterpret_cast<const bf16x8*>(Krow + kOff + 32);
            bf16x8 kf2 = *reinterpret_cast<const bf16x8*>(Krow + kOff + 64);
            bf16x8 kf3 = *reinterpret_cast<const bf16x8*>(Krow + kOff + 96);
            float4 mv = *reinterpret_cast<const float4*>(mPtr);
            __builtin_amdgcn_sched_barrier(0);
            if (t > 0) {
                __builtin_amdgcn_s_setprio(1);
                PV_S(0, pP + 8192, Bva0, Bva1, Bva2, Bva3);
                PV_S(1, pP + 8192, Bvb0, Bvb1, Bvb2, Bvb3);
                __builtin_amdgcn_s_setprio(0);
            }
            __builtin_amdgcn_sched_barrier(0);
            Bva0 = *reinterpret_cast<const bf16x8*>(Vrow + vOff);
            Bva1 = *reinterpret_cast<const bf16x8*>(Vrow + vOff + 16 * BANK);
            Bva2 = *reinterpret_cast<const bf16x8*>(Vrow + vOff + 32 * BANK);
            Bva3 = *reinterpret_cast<const bf16x8*>(Vrow + vOff + 48 * BANK);
            Bvb0 = *reinterpret_cast<const bf16x8*>(Vrow + vOff + 32);
            Bvb1 = *reinterpret_cast<const bf16x8*>(Vrow + vOff + 32 + 16 * BANK);
            Bvb2 = *reinterpret_cast<const bf16x8*>(Vrow + vOff + 32 + 32 * BANK);
            Bvb3 = *reinterpret_cast<const bf16x8*>(Vrow + vOff + 32 + 48 * BANK);
            __builtin_amdgcn_s_setprio(1);
            QK_CG(0, pC + 8192); QK_CG(1, pC + 8192);
            QK_CG(2, pC + 8192); QK_CG(3, pC + 8192);
            __builtin_amdgcn_s_setprio(0);
            Krow += 64 * D_K; Vrow += 64; mPtr += 64;
        }

        // ---- ONE rendezvous per 128 banks: P pair visible, LDS reads done.
        // NO vmcnt — V/K loads drain at consumers via counted waits.
        asm volatile("s_waitcnt lgkmcnt(0)" ::: "memory");
        __builtin_amdgcn_s_barrier();
        __builtin_amdgcn_sched_barrier(0);
    }

    // ---- tail QK (rem==1: 32 banks, waves 0,1) into the free buffer set —
    // issued BEFORE the epilogue PV so its ds_writes hide behind PV.
    char* pT = smem + P_OFF + (npair & 1) * 16384;
    if (rem && wave < 2) {
        bf16x8 kf0 = *reinterpret_cast<const bf16x8*>(Krow + kOff);
        bf16x8 kf1 = *reinterpret_cast<const bf16x8*>(Krow + kOff + 32);
        bf16x8 kf2 = *reinterpret_cast<const bf16x8*>(Krow + kOff + 64);
        bf16x8 kf3 = *reinterpret_cast<const bf16x8*>(Krow + kOff + 96);
        float4 mv = *reinterpret_cast<const float4*>(mPtr);
        QK_CG(0, pT); QK_CG(1, pT); QK_CG(2, pT); QK_CG(3, pT);
    }

    // ---- epilogue PV for the last pair (P visible from final loop barrier)
    {
        const char* pL = smem + P_OFF + (((npair - 1) & 1)) * 16384;
        PV_S(0, pL, Ava0, Ava1, Ava2, Ava3);
        PV_S(1, pL, Avb0, Avb1, Avb2, Avb3);
        PV_S(0, pL + 8192, Bva0, Bva1, Bva2, Bva3);
        PV_S(1, pL + 8192, Bvb0, Bvb1, Bvb2, Bvb3);
    }

    // ---- tail PV
    if (rem) {
        asm volatile("s_waitcnt lgkmcnt(0)" ::: "memory");
        __builtin_amdgcn_s_barrier();
        bf16x8 tv0 = *reinterpret_cast<const bf16x8*>(Vrow + vOff);
        bf16x8 tv1 = *reinterpret_cast<const bf16x8*>(Vrow + vOff + 16 * BANK);
        bf16x8 tv2 = *reinterpret_cast<const bf16x8*>(Vrow + vOff + 32 * BANK);
        bf16x8 tv3 = *reinterpret_cast<const bf16x8*>(Vrow + vOff + 48 * BANK);
        PV_S(0, pT, tv0, tv1, tv2, tv3);
    }

    // ---- l/mm: reduce over q within wave, stage per wave, sum across waves
    float* lst = reinterpret_cast<float*>(smem + LST_OFF);  // [4][64]
    float* mst = reinterpret_cast<float*>(smem + MST_OFF);  // [4][64]
    if (needLM) {
#pragma unroll
        for (int cg = 0; cg < 4; cg++) {
            l_part[cg]  += __shfl_xor(l_part[cg], 16);
            l_part[cg]  += __shfl_xor(l_part[cg], 32);
            mm_part[cg] += __shfl_xor(mm_part[cg], 16);
            mm_part[cg] += __shfl_xor(mm_part[cg], 32);
        }
        if (lane < 16) {
#pragma unroll
            for (int cg = 0; cg < 4; cg++) {
                lst[wave * 64 + 16 * cg + lr] = l_part[cg];
                mst[wave * 64 + 16 * cg + lr] = mm_part[cg];
            }
        }
    }
    __syncthreads();

    if (G == 1) {
        // ---- final epilogue: mem = acc/l ; gated = q_out * (mm/l)
        float* outo = out + (size_t)o * (1024 * NQ);
#pragma unroll
        for (int ng = 0; ng < 4; ng++) {
            const int n  = 16 * ng + lr;
            const int gn = n0 + n;
            if (gn >= NQ) continue;
            const float lsum = lst[n] + lst[64 + n] + lst[128 + n] + lst[192 + n];
            const float msum = mst[n] + mst[64 + n] + mst[128 + n] + mst[192 + n];
            const float invl = 1.f / lsum;
            const float gate = msum * invl;
#pragma unroll
            for (int vt = 0; vt < 4; vt++) {
#pragma unroll
                for (int r = 0; r < 4; r++) {
                    const int v = vh * VH_ROWS + 64 * wave + 16 * vt + 4 * q + r;
                    outo[(size_t)v * NQ + gn] = acc[vt][ng][r] * invl;
                    outo[(size_t)(512 + v) * NQ + gn] = q_out[(size_t)v * NQ + gn] * gate;
                }
            }
        }
    } else {
        // ---- partial epilogue: raw acc into out rows [g*512 .. g*512+511]
        float* dst = out + ((size_t)o * 1024 + (size_t)g * 512 + (size_t)vh * VH_ROWS) * NQ;
#pragma unroll
        for (int ng = 0; ng < 4; ng++) {
            const int n  = 16 * ng + lr;
            const int gn = n0 + n;
            if (gn >= NQ) continue;
#pragma unroll
            for (int vt = 0; vt < 4; vt++) {
#pragma unroll
                for (int r = 0; r < 4; r++) {
                    const int v = 64 * wave + 16 * vt + 4 * q + r;
                    dst[(size_t)v * NQ + gn] = acc[vt][ng][r];
                }
            }
        }
        if (vh == 0 && tid < 64) {
            const size_t li = ((size_t)(g * 4 + o) * NTILES + tile) * 64 + tid;
            lw[li] = lst[tid] + lst[64 + tid] + lst[128 + tid] + lst[192 + tid];
            mw[li] = mst[tid] + mst[64 + tid] + mst[128 + tid] + mst[192 + tid];
        }
    }
}

// ---------------- combine pass (G=2) ----------------
__global__ void k_combine(const float* __restrict__ q_out, const float* __restrict__ lw,
                          const float* __restrict__ mw, float* __restrict__ out) {
    const int total = O_N * 512 * (NQ / 4);   // float4 elements per half-row set
    float4* outv = reinterpret_cast<float4*>(out);
    const float4* qv = reinterpret_cast<const float4*>(q_out);
    for (int idx = blockIdx.x * blockDim.x + threadIdx.x; idx < total;
         idx += gridDim.x * blockDim.x) {
        const int o  = idx / (512 * 900);
        const int r  = idx - o * 512 * 900;
        const int v  = r / 900;
        const int g4 = r - v * 900;
        const size_t iA = ((size_t)o * 1024 + v) * 900 + g4;
        const size_t iB = ((size_t)o * 1024 + 512 + v) * 900 + g4;
        float4 A = outv[iA];
        float4 B = outv[iB];
        const int tl = g4 >> 4;
        const int wi = (g4 & 15) * 4;
        const size_t l0i = ((size_t)(0 * 4 + o) * NTILES + tl) * 64 + wi;
        const size_t l1i = ((size_t)(1 * 4 + o) * NTILES + tl) * 64 + wi;
        const float4 l0 = *reinterpret_cast<const float4*>(lw + l0i);
        const float4 l1 = *reinterpret_cast<const float4*>(lw + l1i);
        const float4 m0 = *reinterpret_cast<const float4*>(mw + l0i);
        const float4 m1 = *reinterpret_cast<const float4*>(mw + l1i);
        float4 li, mem, gate;
        li.x = 1.f / (l0.x + l1.x); li.y = 1.f / (l0.y + l1.y);
        li.z = 1.f / (l0.z + l1.z); li.w = 1.f / (l0.w + l1.w);
        mem.x = (A.x + B.x) * li.x; mem.y = (A.y + B.y) * li.y;
        mem.z = (A.z + B.z) * li.z; mem.w = (A.w + B.w) * li.w;
        gate.x = (m0.x + m1.x) * li.x; gate.y = (m0.y + m1.y) * li.y;
        gate.z = (m0.z + m1.z) * li.z; gate.w = (m0.w + m1.w) * li.w;
        float4 qo = qv[(size_t)v * 900 + g4];
        outv[iA] = mem;
        float4 gq;
        gq.x = qo.x * gate.x; gq.y = qo.y * gate.y;
        gq.z = qo.z * gate.z; gq.w = qo.w * gate.w;
        outv[iB] = gq;
    }
}

extern "C" void kernel_launch(void* const* d_in, const int* in_sizes, int n_in,
                              void* d_out, int out_size, void* d_ws, size_t ws_size,
                              hipStream_t stream) {
    const float* keys   = (const float*)d_in[0];
    const float* values = (const float*)d_in[1];
    const float* masks  = (const float*)d_in[2];
    const float* q_in   = (const float*)d_in[3];
    const float* q_outp = (const float*)d_in[4];
    float* out = (float*)d_out;

    const size_t K_BYTES  = (size_t)O_N * BANK * D_K * 2;   //  7,372,800
    const size_t V_BYTES  = (size_t)O_N * D_V * BANK * 2;   // 29,491,200
    const size_t LM_FLOATS = (size_t)2 * O_N * NTILES * 64; // per array (G=2)
    const size_t LM_BYTES  = LM_FLOATS * 4 * 2;             // l + mm

    if (ws_size < K_BYTES + V_BYTES) {
        k_zero<<<(out_size + 255) / 256, 256, 0, stream>>>(out, out_size);
        return;
    }
    const int G = (ws_size >= K_BYTES + V_BYTES + LM_BYTES) ? 2 : 1;

    u16* Kt = (u16*)d_ws;
    u16* Vb = (u16*)((char*)d_ws + K_BYTES);
    float* lw = (float*)((char*)d_ws + K_BYTES + V_BYTES);
    float* mw = lw + LM_FLOATS;

    dim3 tb(32, 8);
    dim3 tg(BANK / 32, D_K / 32, O_N);
    k_transpose_bf16<<<tg, tb, 0, stream>>>(keys, Kt);

    const int n4 = O_N * D_V * BANK / 4;
    k_convert_bf16<<<2048, 256, 0, stream>>>(values, Vb, n4);

    k_matcher<<<NTILES * 8 * G, 256, 0, stream>>>(Kt, Vb, masks, q_in, q_outp, out,
                                                  G, lw, mw);
    if (G == 2)
        k_combine<<<2048, 256, 0, stream>>>(q_outp, lw, mw, out);
}

// Round 19
// 288.472 us; speedup vs baseline: 1.3381x; 1.3381x over previous
//
#include <hip/hip_runtime.h>
#include <hip/hip_bf16.h>

typedef unsigned short u16;
typedef unsigned int   u32;
typedef short bf16x8 __attribute__((ext_vector_type(8)));
typedef float f32x4  __attribute__((ext_vector_type(4)));

#define O_N    4
#define D_K    128
#define D_V    512
#define BANK   7200
#define NQ     3600
#define NT     64            // query columns per block
#define NTILES 57            // ceil(3600/64)
#define NSUB   225           // 7200 / 32 sub-tiles
#define VH_ROWS 256          // v rows per block (half of 512)

// ---- LDS layout (bytes). K is NOT staged in LDS (global->reg like V):
// per-unit LDS traffic is P exchange only (40KB/unit).
#define P_OFF    0           // P dbuf: 2 x [64 n][64 b] bf16, 128B rows (2 x 8192)
#define LST_OFF  16384       // l stage [4 waves][64 n] f32 (1024)
#define MST_OFF  17408       // mm stage [4][64] f32 (1024)
#define SMEM_BYTES 18432
#define Q_OFF    0           // Q tile [64 n][128 d] bf16 (16KB) overlaps P dbuf; prologue only

#define MFMA16(a, b, c) __builtin_amdgcn_mfma_f32_16x16x32_bf16((a), (b), (c), 0, 0, 0)

static __device__ __forceinline__ u16 f2bf(float x) {
    u32 u = __builtin_bit_cast(u32, x);
    return (u16)((u + 0x7FFFu + ((u >> 16) & 1u)) >> 16);
}

// Q-side scale fold: stage Q * (log2e / sqrt(128)) so softmax exp is bare exp2f.
#define QSCALE 0.12751743f

// ---------------- preconv kernels ----------------

__global__ void k_transpose_bf16(const float* __restrict__ in, u16* __restrict__ out) {
    __shared__ float tile[32][33];
    const int obj = blockIdx.z;
    const float* src = in + (size_t)obj * D_K * BANK;
    u16* dst = out + (size_t)obj * BANK * D_K;
    const int bx = blockIdx.x * 32;   // bank
    const int by = blockIdx.y * 32;   // d
    const int tx = threadIdx.x, ty = threadIdx.y;  // 32 x 8
#pragma unroll
    for (int i = 0; i < 4; i++)
        tile[ty + 8 * i][tx] = src[(size_t)(by + ty + 8 * i) * BANK + bx + tx];
    __syncthreads();
#pragma unroll
    for (int i = 0; i < 4; i++)
        dst[(size_t)(bx + ty + 8 * i) * D_K + by + tx] = f2bf(tile[tx][ty + 8 * i]);
}

__global__ void k_convert_bf16(const float* __restrict__ in, u16* __restrict__ out, int n4) {
    int idx = blockIdx.x * blockDim.x + threadIdx.x;
    int stride = gridDim.x * blockDim.x;
    for (int i = idx; i < n4; i += stride) {
        float4 v = reinterpret_cast<const float4*>(in)[i];
        ushort4 o;
        o.x = f2bf(v.x); o.y = f2bf(v.y); o.z = f2bf(v.z); o.w = f2bf(v.w);
        reinterpret_cast<ushort4*>(out)[i] = o;
    }
}

__global__ void k_zero(float* out, int n) {
    int i = blockIdx.x * blockDim.x + threadIdx.x;
    if (i < n) out[i] = 0.f;
}

// ---------------- main fused kernel ----------------
// blockIdx.x = ((tile*G + g) << 3) | (o*2+vh): (o,vh) pinned per XCD for L2.
//
// FINAL (R16, session best 288.9us): QK split by BANKS across waves (wave
// owns 16 banks/unit), K/V global->reg, P exchanged via LDS dbuf. ONE
// barrier per 64-bank unit, lgkmcnt(0) only — no vmcnt fences; K/V loads
// drain at consumers via compiler-counted waits. T5 setprio on MFMA
// clusters (null but harmless). 2 blocks/CU (129-256 unified-reg band is
// structural: qf64+acc64 state floor makes 170-reg/3-wave unreachable —
// R13/R14/R18 all confirmed).
__launch_bounds__(256, 2)
__global__ void k_matcher(const u16* __restrict__ Kt,     // [O][7200][128] bf16
                          const u16* __restrict__ Vb,     // [O][512][7200] bf16
                          const float* __restrict__ masks,// [O][7200]
                          const float* __restrict__ q_in, // [128][3600]
                          const float* __restrict__ q_out,// [512][3600]
                          float* __restrict__ out,        // [O][1024][3600]
                          int G, float* __restrict__ lw, float* __restrict__ mw)
{
    __shared__ __align__(16) char smem[SMEM_BYTES];
    const int tid  = threadIdx.x;
    const int wave = tid >> 6;
    const int lane = tid & 63;
    const int q    = lane >> 4;
    const int lr   = lane & 15;
    const int lr7  = lr & 7;

    const int grp  = blockIdx.x & 7;
    const int o    = grp >> 1;
    const int vh   = grp & 1;
    const int rest = blockIdx.x >> 3;
    const int tile = rest / G;
    const int g    = rest - tile * G;
    const int n0   = tile * NT;

    const bool needLM = (G == 1) || (vh == 0);

    // sub-tile (32-bank) range; units = doubles (64 banks) + optional 32-bank tail
    const int st0 = (NSUB * g) / G;
    const int st1 = (NSUB * (g + 1)) / G;
    const int cnt = st1 - st0;
    const int nd  = cnt >> 1;
    const int ts  = cnt & 1;
    const int nu  = nd + ts;

    // ---- stage Q tile (pre-scaled): Q_lds[n][d] bf16, granule swizzle ^ (n&7)
    for (int idx = tid; idx < NT * D_K; idx += 256) {
        int d = idx >> 6;
        int n = idx & 63;
        int gn = n0 + n;
        float v = (gn < NQ) ? q_in[(size_t)d * NQ + gn] * QSCALE : 0.f;
        int bb = d * 2;
        int sb = n * 256 + ((((bb >> 4) ^ (n & 7)) << 4) | (bb & 15));
        *reinterpret_cast<u16*>(smem + Q_OFF + sb) = f2bf(v);
    }
    __syncthreads();

    // ---- Q fragments for ALL 4 column groups (qf[cg][ds], 64 VGPRs)
    bf16x8 qf[4][4];
#pragma unroll
    for (int cg = 0; cg < 4; cg++)
#pragma unroll
        for (int ds = 0; ds < 4; ds++) {
            int gq = (4 * ds + q) ^ lr7;   // (16cg+lr)&7 == lr7
            qf[cg][ds] = *reinterpret_cast<const bf16x8*>(
                smem + Q_OFF + (16 * cg + lr) * 256 + gq * 16);
        }
    __syncthreads();   // Q region about to be overwritten by P tiles

    const f32x4 zero4 = {0.f, 0.f, 0.f, 0.f};
    f32x4 acc[4][4];
#pragma unroll
    for (int i = 0; i < 4; i++)
#pragma unroll
        for (int j = 0; j < 4; j++) acc[i][j] = zero4;
    float l_part[4]  = {0.f, 0.f, 0.f, 0.f};
    float mm_part[4] = {0.f, 0.f, 0.f, 0.f};

    const u16* Ko = Kt + (size_t)o * BANK * D_K;
    const u16* Vo = Vb + (size_t)o * D_V * BANK + (size_t)vh * VH_ROWS * BANK;

    // K direct-to-register: uniform advancing base + per-lane offset.
    const u16* Krow = Ko + (size_t)(st0 * 32) * D_K;
    const u32  kOff = (u32)(16 * wave + lr) * D_K + q * 8;

    // V direct-to-register: wave owns v rows [64w, 64w+64).
    const u16* Vrow = Vo + st0 * 32;
    const u32  vOff = (u32)(64 * wave + lr) * BANK + q * 8;

    // mask: lane's banks are ub + 16*wave + 4*q + r (r=0..3)
    const float* mPtr = masks + (size_t)o * BANK + st0 * 32 + 16 * wave + 4 * q;

// QK for one column group CG: 4 MFMA over d, exp2, l/mm, cvt_pk, b64 P write.
#define QK_CG(CG) do {                                                       \
        f32x4 s_acc = zero4;                                                 \
        s_acc = MFMA16(kf0, qf[CG][0], s_acc);                               \
        s_acc = MFMA16(kf1, qf[CG][1], s_acc);                               \
        s_acc = MFMA16(kf2, qf[CG][2], s_acc);                               \
        s_acc = MFMA16(kf3, qf[CG][3], s_acc);                               \
        float p0 = exp2f(s_acc[0]);                                          \
        float p1 = exp2f(s_acc[1]);                                          \
        float p2 = exp2f(s_acc[2]);                                          \
        float p3 = exp2f(s_acc[3]);                                          \
        if (needLM) {                                                        \
            l_part[CG]  += p0 + p1 + p2 + p3;                                \
            mm_part[CG] += p0 * mv.x + p1 * mv.y + p2 * mv.z + p3 * mv.w;    \
        }                                                                    \
        u32 w0, w1;                                                          \
        asm("v_cvt_pk_bf16_f32 %0, %1, %2" : "=v"(w0) : "v"(p0), "v"(p1));   \
        asm("v_cvt_pk_bf16_f32 %0, %1, %2" : "=v"(w1) : "v"(p2), "v"(p3));   \
        uint2 pk2; pk2.x = w0; pk2.y = w1;                                   \
        *reinterpret_cast<uint2*>(pWb + (16 * (CG) + lr) * 128 +             \
            (((2 * wave + (q >> 1)) ^ lr7) << 4) + (q & 1) * 8) = pk2;       \
    } while (0)

// PV for one 32-bank sub S from P buffer PB with V frags V0..V3
#define PV_S(S, PB, V0, V1, V2, V3) do {                                     \
        _Pragma("unroll")                                                    \
        for (int ng = 0; ng < 4; ng++) {                                     \
            bf16x8 pf = *reinterpret_cast<const bf16x8*>(                    \
                (PB) + (16 * ng + lr) * 128 +                                \
                (((4 * (S) + q) ^ lr7) << 4));                               \
            acc[0][ng] = MFMA16(V0, pf, acc[0][ng]);                         \
            acc[1][ng] = MFMA16(V1, pf, acc[1][ng]);                         \
            acc[2][ng] = MFMA16(V2, pf, acc[2][ng]);                         \
            acc[3][ng] = MFMA16(V3, pf, acc[3][ng]);                         \
        }                                                                    \
    } while (0)

    bf16x8 va0, va1, va2, va3, vb0, vb1, vb2, vb3;

    for (int u = 0; u < nu; u++) {
        const int cur = u & 1;
        char* pWb = smem + P_OFF + cur * 8192;
        const char* pR = smem + P_OFF + (cur ^ 1) * 8192;
        const bool full = (u < nd);
        const bool doQK = full || (wave < 2);   // tail unit: 32 banks = waves 0,1

        // ---- 1) issue K(u) frags + mask (kf dead since last phase's QK)
        bf16x8 kf0, kf1, kf2, kf3;
        float4 mv;
        if (doQK) {
            kf0 = *reinterpret_cast<const bf16x8*>(Krow + kOff);
            kf1 = *reinterpret_cast<const bf16x8*>(Krow + kOff + 32);
            kf2 = *reinterpret_cast<const bf16x8*>(Krow + kOff + 64);
            kf3 = *reinterpret_cast<const bf16x8*>(Krow + kOff + 96);
            mv  = *reinterpret_cast<const float4*>(mPtr);
        }
        __builtin_amdgcn_sched_barrier(0);

        // ---- 2) PV(u-1) from P[prev] — covers K load latency.
        //         T5: raise priority for the MFMA cluster.
        if (u > 0) {
            __builtin_amdgcn_s_setprio(1);
            PV_S(0, pR, va0, va1, va2, va3);
            PV_S(1, pR, vb0, vb1, vb2, vb3);
            __builtin_amdgcn_s_setprio(0);
        }
        __builtin_amdgcn_sched_barrier(0);   // V loads below reuse va/vb regs

        // ---- 3) issue V(u) into va/vb (consumed next phase; QK+barrier cover)
        va0 = *reinterpret_cast<const bf16x8*>(Vrow + vOff);
        va1 = *reinterpret_cast<const bf16x8*>(Vrow + vOff + 16 * BANK);
        va2 = *reinterpret_cast<const bf16x8*>(Vrow + vOff + 32 * BANK);
        va3 = *reinterpret_cast<const bf16x8*>(Vrow + vOff + 48 * BANK);
        if (full) {
            vb0 = *reinterpret_cast<const bf16x8*>(Vrow + vOff + 32);
            vb1 = *reinterpret_cast<const bf16x8*>(Vrow + vOff + 32 + 16 * BANK);
            vb2 = *reinterpret_cast<const bf16x8*>(Vrow + vOff + 32 + 32 * BANK);
            vb3 = *reinterpret_cast<const bf16x8*>(Vrow + vOff + 32 + 48 * BANK);
        }

        // ---- 4) QK(u): S[wave's 16 banks][all 64 cols] -> P[cur]
        //         T5: priority on (MFMA-dominant cluster; exp/cvt interleaved)
        if (doQK) {
            __builtin_amdgcn_s_setprio(1);
            QK_CG(0); QK_CG(1); QK_CG(2); QK_CG(3);
            __builtin_amdgcn_s_setprio(0);
        }

        Vrow += full ? 64 : 32;
        Krow += (full ? 64 : 32) * D_K;
        mPtr += full ? 64 : 32;

        // ---- end fence: P[cur] writes + LDS reads done. NO vmcnt — V loads
        // stay in flight across the barrier.
        asm volatile("s_waitcnt lgkmcnt(0)" ::: "memory");
        __builtin_amdgcn_s_barrier();
        __builtin_amdgcn_sched_barrier(0);
    }

    // ---- epilogue PV for the last unit
    {
        const char* pL = smem + P_OFF + ((nu - 1) & 1) * 8192;
        PV_S(0, pL, va0, va1, va2, va3);
        if (!ts) PV_S(1, pL, vb0, vb1, vb2, vb3);
    }

    // ---- l/mm: reduce over q within wave, stage per wave, sum across waves
    float* lst = reinterpret_cast<float*>(smem + LST_OFF);  // [4][64]
    float* mst = reinterpret_cast<float*>(smem + MST_OFF);  // [4][64]
    if (needLM) {
#pragma unroll
        for (int cg = 0; cg < 4; cg++) {
            l_part[cg]  += __shfl_xor(l_part[cg], 16);
            l_part[cg]  += __shfl_xor(l_part[cg], 32);
            mm_part[cg] += __shfl_xor(mm_part[cg], 16);
            mm_part[cg] += __shfl_xor(mm_part[cg], 32);
        }
        if (lane < 16) {
#pragma unroll
            for (int cg = 0; cg < 4; cg++) {
                lst[wave * 64 + 16 * cg + lr] = l_part[cg];
                mst[wave * 64 + 16 * cg + lr] = mm_part[cg];
            }
        }
    }
    __syncthreads();

    if (G == 1) {
        // ---- final epilogue: mem = acc/l ; gated = q_out * (mm/l)
        float* outo = out + (size_t)o * (1024 * NQ);
#pragma unroll
        for (int ng = 0; ng < 4; ng++) {
            const int n  = 16 * ng + lr;
            const int gn = n0 + n;
            if (gn >= NQ) continue;
            const float lsum = lst[n] + lst[64 + n] + lst[128 + n] + lst[192 + n];
            const float msum = mst[n] + mst[64 + n] + mst[128 + n] + mst[192 + n];
            const float invl = 1.f / lsum;
            const float gate = msum * invl;
#pragma unroll
            for (int vt = 0; vt < 4; vt++) {
#pragma unroll
                for (int r = 0; r < 4; r++) {
                    const int v = vh * VH_ROWS + 64 * wave + 16 * vt + 4 * q + r;
                    outo[(size_t)v * NQ + gn] = acc[vt][ng][r] * invl;
                    outo[(size_t)(512 + v) * NQ + gn] = q_out[(size_t)v * NQ + gn] * gate;
                }
            }
        }
    } else {
        // ---- partial epilogue: raw acc into out rows [g*512 .. g*512+511]
        float* dst = out + ((size_t)o * 1024 + (size_t)g * 512 + (size_t)vh * VH_ROWS) * NQ;
#pragma unroll
        for (int ng = 0; ng < 4; ng++) {
            const int n  = 16 * ng + lr;
            const int gn = n0 + n;
            if (gn >= NQ) continue;
#pragma unroll
            for (int vt = 0; vt < 4; vt++) {
#pragma unroll
                for (int r = 0; r < 4; r++) {
                    const int v = 64 * wave + 16 * vt + 4 * q + r;
                    dst[(size_t)v * NQ + gn] = acc[vt][ng][r];
                }
            }
        }
        if (vh == 0 && tid < 64) {
            const size_t li = ((size_t)(g * 4 + o) * NTILES + tile) * 64 + tid;
            lw[li] = lst[tid] + lst[64 + tid] + lst[128 + tid] + lst[192 + tid];
            mw[li] = mst[tid] + mst[64 + tid] + mst[128 + tid] + mst[192 + tid];
        }
    }
}

// ---------------- combine pass (G=2) ----------------
__global__ void k_combine(const float* __restrict__ q_out, const float* __restrict__ lw,
                          const float* __restrict__ mw, float* __restrict__ out) {
    const int total = O_N * 512 * (NQ / 4);   // float4 elements per half-row set
    float4* outv = reinterpret_cast<float4*>(out);
    const float4* qv = reinterpret_cast<const float4*>(q_out);
    for (int idx = blockIdx.x * blockDim.x + threadIdx.x; idx < total;
         idx += gridDim.x * blockDim.x) {
        const int o  = idx / (512 * 900);
        const int r  = idx - o * 512 * 900;
        const int v  = r / 900;
        const int g4 = r - v * 900;
        const size_t iA = ((size_t)o * 1024 + v) * 900 + g4;
        const size_t iB = ((size_t)o * 1024 + 512 + v) * 900 + g4;
        float4 A = outv[iA];
        float4 B = outv[iB];
        const int tl = g4 >> 4;
        const int wi = (g4 & 15) * 4;
        const size_t l0i = ((size_t)(0 * 4 + o) * NTILES + tl) * 64 + wi;
        const size_t l1i = ((size_t)(1 * 4 + o) * NTILES + tl) * 64 + wi;
        const float4 l0 = *reinterpret_cast<const float4*>(lw + l0i);
        const float4 l1 = *reinterpret_cast<const float4*>(lw + l1i);
        const float4 m0 = *reinterpret_cast<const float4*>(mw + l0i);
        const float4 m1 = *reinterpret_cast<const float4*>(mw + l1i);
        float4 li, mem, gate;
        li.x = 1.f / (l0.x + l1.x); li.y = 1.f / (l0.y + l1.y);
        li.z = 1.f / (l0.z + l1.z); li.w = 1.f / (l0.w + l1.w);
        mem.x = (A.x + B.x) * li.x; mem.y = (A.y + B.y) * li.y;
        mem.z = (A.z + B.z) * li.z; mem.w = (A.w + B.w) * li.w;
        gate.x = (m0.x + m1.x) * li.x; gate.y = (m0.y + m1.y) * li.y;
        gate.z = (m0.z + m1.z) * li.z; gate.w = (m0.w + m1.w) * li.w;
        float4 qo = qv[(size_t)v * 900 + g4];
        outv[iA] = mem;
        float4 gq;
        gq.x = qo.x * gate.x; gq.y = qo.y * gate.y;
        gq.z = qo.z * gate.z; gq.w = qo.w * gate.w;
        outv[iB] = gq;
    }
}

extern "C" void kernel_launch(void* const* d_in, const int* in_sizes, int n_in,
                              void* d_out, int out_size, void* d_ws, size_t ws_size,
                              hipStream_t stream) {
    const float* keys   = (const float*)d_in[0];
    const float* values = (const float*)d_in[1];
    const float* masks  = (const float*)d_in[2];
    const float* q_in   = (const float*)d_in[3];
    const float* q_outp = (const float*)d_in[4];
    float* out = (float*)d_out;

    const size_t K_BYTES  = (size_t)O_N * BANK * D_K * 2;   //  7,372,800
    const size_t V_BYTES  = (size_t)O_N * D_V * BANK * 2;   // 29,491,200
    const size_t LM_FLOATS = (size_t)2 * O_N * NTILES * 64; // per array (G=2)
    const size_t LM_BYTES  = LM_FLOATS * 4 * 2;             // l + mm

    if (ws_size < K_BYTES + V_BYTES) {
        k_zero<<<(out_size + 255) / 256, 256, 0, stream>>>(out, out_size);
        return;
    }
    const int G = (ws_size >= K_BYTES + V_BYTES + LM_BYTES) ? 2 : 1;

    u16* Kt = (u16*)d_ws;
    u16* Vb = (u16*)((char*)d_ws + K_BYTES);
    float* lw = (float*)((char*)d_ws + K_BYTES + V_BYTES);
    float* mw = lw + LM_FLOATS;

    dim3 tb(32, 8);
    dim3 tg(BANK / 32, D_K / 32, O_N);
    k_transpose_bf16<<<tg, tb, 0, stream>>>(keys, Kt);

    const int n4 = O_N * D_V * BANK / 4;
    k_convert_bf16<<<2048, 256, 0, stream>>>(values, Vb, n4);

    k_matcher<<<NTILES * 8 * G, 256, 0, stream>>>(Kt, Vb, masks, q_in, q_outp, out,
                                                  G, lw, mw);
    if (G == 2)
        k_combine<<<2048, 256, 0, stream>>>(q_outp, lw, mw, out);
}